// Round 9
// baseline (1027.269 us; speedup 1.0000x reference)
//
#include <hip/hip_runtime.h>

// Problem constants (fixed by the reference)
#define P 8
#define T 200
#define C 20
#define F 512
#define NQ 1024
#define MAXN 40                    // max samples per class we support (true ~10±4)
#define MMAX (T + MAXN)            // 240
#define PACK ((MMAX*(MMAX+1))/2)   // 28920 packed lower-tri floats
#define PACKA 29280                // row-padded-to-4 packed layout = rowS(MMAX) (LDS layout)
#define PACKT 40960                // tile-padded layout: row r padded to ((r>>6)+1)*64 cols (global W)
#define QL (NQ*C)                  // 20480 logits
#define NB 16                      // Cholesky panel width
#define NTF 512                    // k_factor block size (8 waves; 1024 forced VGPR<=64 -> spills, R7)

// Workspace layout (float offsets)
enum : int {
  OFF_G    = 0,                       // P*T*T      = 320000
  OFF_SQ   = OFF_G   + P*T*T,         // P*T*NQ     = 1638400
  OFF_G1   = OFF_SQ  + P*T*NQ,        // P*T
  OFF_GG   = OFF_G1  + P*T,           // P
  OFF_GM   = OFF_GG  + P,             // P*T*C
  OFF_GMC  = OFF_GM  + P*T*C,         // P*C
  OFF_MM   = OFF_GMC + P*C,           // P*C
  OFF_GQ   = OFF_MM  + P*C,           // P*NQ
  OFF_QN   = OFF_GQ  + P*NQ,          // P*NQ
  OFF_MQ   = OFF_QN  + P*NQ,          // P*C*NQ
  OFF_W    = OFF_MQ  + P*C*NQ,        // P*C*PACKT : W=L^-1, tile-padded rows, zeros beyond diag & rows>=m
  OFF_QUAD = OFF_W   + P*C*PACKT,     // P*NQ*C
  OFF_CLSF = OFF_QUAD+ P*NQ*C,        // C*8 scalars
  OFF_INT  = OFF_CLSF+ C*8            // int region: counts[C], idx[C*MAXN]
};

__device__ __forceinline__ int offr(int i){ return (i*(i+1))>>1; }

// 4-aligned row-padded packed layout (LDS): row i at rowS(i).
__device__ __forceinline__ int rowS(int i){
  int a = i >> 2, r = i & 3;
  return 8*a*(a+1) + 4*r*(a+1);
}

// tile-padded layout (global W): row r at rowT(r), length ((r>>6)+1)*64.
__device__ __forceinline__ int rowT(int r){
  const int R = r >> 6, s = r & 63;
  const int base = 4096 * ((R*(R+1)) >> 1);   // 0,4096,12288,24576
  return base + s*((R+1) << 6);
}

// flat packed index e -> row i (offr layout, used for tile triangles)
__device__ __forceinline__ int row_of(int e){
  int i = (int)((sqrtf(8.f*(float)e + 1.f) - 1.f) * 0.5f);
  while (offr(i+1) <= e) ++i;
  while (offr(i) > e) --i;
  return i;
}

// flat index e -> row i in rowS layout
__device__ __forceinline__ int row_ofS(int e){
  int i = (int)sqrtf(2.f*(float)e);
  if (i > MMAX-1) i = MMAX-1;
  while (i < MMAX-1 && rowS(i+1) <= e) ++i;
  while (i > 0 && rowS(i) > e) --i;
  return i;
}

// ---------------- setup: counts, per-class index lists, scalars ----------------
__global__ void k_setup(const int* lab, float* ws){
  int c = threadIdx.x;
  if (c >= C) return;
  int* wsI = (int*)(ws + OFF_INT);
  int n = 0;
  for (int t = 0; t < T; ++t){
    if (lab[t] == c){ if (n < MAXN) wsI[C + c*MAXN + n] = t; ++n; }
  }
  if (n > MAXN) n = MAXN;
  wsI[c] = n;
  float nf    = (float)n;
  float nsafe = fmaxf(nf, 1.0f);
  float dn    = fmaxf(nf - 1.0f, 1.0f);
  float lam   = nsafe / (nsafe + 1.0f);
  float sv    = (1.0f - lam) / (float)(T - 1);
  float av    = lam / dn;
  float* cf = ws + OFF_CLSF + c*8;
  cf[0] = nsafe; cf[1] = dn; cf[2] = lam; cf[3] = sv; cf[4] = av;
  cf[5] = sqrtf(sv); cf[6] = sqrtf(av); cf[7] = 0.0f;
}

// ---------------- G = X X^T per p (200x200) ----------------
__global__ __launch_bounds__(256) void k_gram(const float* X, float* ws){
  __shared__ float Xi[32][33];
  __shared__ float Xj[32][33];
  const int p = blockIdx.z, i0 = blockIdx.y*32, j0 = blockIdx.x*32;
  const int tx = threadIdx.x, ty = threadIdx.y;
  const int tid = ty*16 + tx;
  const float* Xp = X + (size_t)p*T*F;
  float acc[2][2] = {{0.f,0.f},{0.f,0.f}};
  for (int kb = 0; kb < F; kb += 32){
    for (int e = tid; e < 32*32; e += 256){
      int r = e >> 5, kk = e & 31;
      Xi[r][kk] = (i0+r < T) ? Xp[(i0+r)*F + kb+kk] : 0.f;
      Xj[r][kk] = (j0+r < T) ? Xp[(j0+r)*F + kb+kk] : 0.f;
    }
    __syncthreads();
    for (int kk = 0; kk < 32; ++kk){
      float a0 = Xi[2*ty][kk],   a1 = Xi[2*ty+1][kk];
      float b0 = Xj[2*tx][kk],   b1 = Xj[2*tx+1][kk];
      acc[0][0] += a0*b0; acc[0][1] += a0*b1;
      acc[1][0] += a1*b0; acc[1][1] += a1*b1;
    }
    __syncthreads();
  }
  float* Gp = ws + OFF_G + (size_t)p*T*T;
  for (int a = 0; a < 2; ++a)
    for (int b = 0; b < 2; ++b){
      int i = i0 + 2*ty + a, j = j0 + 2*tx + b;
      if (i < T && j < T) Gp[i*T + j] = acc[a][b];
    }
}

// ---------------- per-p stats part A: g1 rows + Gm (coalesced, 200 blocks) ----------------
__global__ __launch_bounds__(256) void k_pstats_a(float* ws){
  const int p = blockIdx.y, bx = blockIdx.x;      // bx in [0,25)
  const int w = threadIdx.x >> 6, lane = threadIdx.x & 63;
  const int* wsI = (const int*)(ws + OFF_INT);
  const float* Gp = ws + OFF_G + (size_t)p*T*T;
  float* g1 = ws + OFF_G1 + p*T;
  float* Gm = ws + OFF_GM + (size_t)p*T*C;
  for (int rr = 0; rr < 2; ++rr){
    const int t = bx*8 + w*2 + rr;                // 25*8 = 200 rows exactly
    float s = 0.f;
    for (int u = lane; u < T; u += 64) s += Gp[t*T + u];
    for (int off = 32; off; off >>= 1) s += __shfl_down(s, off, 64);
    if (lane == 0) g1[t] = s * (1.0f/T);
    if (lane < C){
      int c = lane, nn = wsI[c];
      const int* idxc = wsI + C + c*MAXN;
      float sc = 0.f;
      for (int j = 0; j < nn; ++j) sc += Gp[t*T + idxc[j]];
      Gm[t*C + c] = sc / ws[OFF_CLSF + c*8];
    }
  }
}

// ---------------- per-p stats part B: gg, gmc, mm ----------------
__global__ __launch_bounds__(256) void k_pstats_b(float* ws){
  __shared__ float red[64];
  const int p = blockIdx.x, tid = threadIdx.x;
  const int* wsI = (const int*)(ws + OFF_INT);
  const float* g1 = ws + OFF_G1 + p*T;
  const float* Gm = ws + OFF_GM + (size_t)p*T*C;
  if (tid < 64){
    float s = 0.f;
    for (int t = tid; t < T; t += 64) s += g1[t];
    red[tid] = s;
  }
  __syncthreads();
  if (tid == 0){
    float s = 0.f;
    for (int k = 0; k < 64; ++k) s += red[k];
    ws[OFF_GG + p] = s * (1.0f/T);
  }
  if (tid < C){
    int c = tid, nn = wsI[c];
    const int* idxc = wsI + C + c*MAXN;
    float s = 0.f;
    for (int t = 0; t < T; ++t) s += Gm[t*C + c];
    ws[OFF_GMC + p*C + c] = s * (1.0f/T);
    float s2 = 0.f;
    for (int j = 0; j < nn; ++j) s2 += Gm[idxc[j]*C + c];
    ws[OFF_MM + p*C + c] = s2 / ws[OFF_CLSF + c*8];
  }
}

// ---------------- class means -> output part 2 ----------------
__global__ __launch_bounds__(256) void k_means(const float* X, const float* ws, float* out){
  const int blk = blockIdx.x, p = blk / C, c = blk % C;
  const int* wsI = (const int*)(ws + OFF_INT);
  const int n = wsI[c];
  const int* idxc = wsI + C + c*MAXN;
  const float nf = ws[OFF_CLSF + c*8];
  const float* Xp = X + (size_t)p*T*F;
  float* o = out + QL + (size_t)(p*C + c)*F;
  for (int f = threadIdx.x; f < F; f += 256){
    float s = 0.f;
    for (int j = 0; j < n; ++j) s += Xp[idxc[j]*F + f];
    o[f] = s / nf;
  }
}

// ---------------- SQ = X Q^T per p (200x1024) ----------------
__global__ __launch_bounds__(256) void k_sq(const float* X, const float* Qf, float* ws){
  __shared__ float Xt[32][33];
  __shared__ float Qt[64][33];
  const int p = blockIdx.z, t0 = blockIdx.x*32, q0 = blockIdx.y*64;
  const int tx = threadIdx.x, ty = threadIdx.y;
  const int tid = ty*16 + tx;
  const float* Xp = X  + (size_t)p*T*F;
  const float* Qp = Qf + (size_t)p*NQ*F;
  float acc[2][4] = {};
  for (int kb = 0; kb < F; kb += 32){
    for (int e = tid; e < 32*32; e += 256){
      int r = e >> 5, kk = e & 31;
      Xt[r][kk] = (t0+r < T) ? Xp[(t0+r)*F + kb+kk] : 0.f;
    }
    for (int e = tid; e < 64*32; e += 256){
      int r = e >> 5, kk = e & 31;
      Qt[r][kk] = Qp[(q0+r)*F + kb+kk];
    }
    __syncthreads();
    for (int kk = 0; kk < 32; ++kk){
      float a0 = Xt[2*ty][kk], a1 = Xt[2*ty+1][kk];
      float b0 = Qt[4*tx][kk], b1 = Qt[4*tx+1][kk], b2 = Qt[4*tx+2][kk], b3 = Qt[4*tx+3][kk];
      acc[0][0] += a0*b0; acc[0][1] += a0*b1; acc[0][2] += a0*b2; acc[0][3] += a0*b3;
      acc[1][0] += a1*b0; acc[1][1] += a1*b1; acc[1][2] += a1*b2; acc[1][3] += a1*b3;
    }
    __syncthreads();
  }
  float* SQp = ws + OFF_SQ + (size_t)p*T*NQ;
  for (int a = 0; a < 2; ++a){
    int t = t0 + 2*ty + a;
    if (t < T)
      for (int b = 0; b < 4; ++b)
        SQp[t*NQ + q0 + 4*tx + b] = acc[a][b];
  }
}

// ---------------- per-q stats: gq, mq (chunked, 128 blocks) ----------------
__global__ __launch_bounds__(256) void k_qstats(float* ws){
  __shared__ float red[4][64];
  const int p = blockIdx.y;
  const int qb = blockIdx.x*64;                   // gridDim.x = 16
  const int chunk = threadIdx.x >> 6, lane = threadIdx.x & 63;
  const int q = qb + lane;
  const int* wsI = (const int*)(ws + OFF_INT);
  const float* SQp = ws + OFF_SQ + (size_t)p*T*NQ;
  float s = 0.f;
  for (int t = chunk*50; t < chunk*50 + 50; ++t) s += SQp[t*NQ + q];
  red[chunk][lane] = s;
  __syncthreads();
  if (chunk == 0){
    float tot = red[0][lane] + red[1][lane] + red[2][lane] + red[3][lane];
    ws[OFF_GQ + p*NQ + q] = tot * (1.0f/T);
  }
  for (int c = chunk; c < C; c += 4){
    int nn = wsI[c];
    const int* idxc = wsI + C + c*MAXN;
    float sc = 0.f;
    for (int j = 0; j < nn; ++j) sc += SQp[idxc[j]*NQ + q];
    ws[OFF_MQ + ((size_t)(p*C + c))*NQ + q] = sc / ws[OFF_CLSF + c*8];
  }
}

// ---------------- qn = ||q||^2, one wave per row ----------------
__global__ __launch_bounds__(256) void k_qnorm(const float* Qf, float* ws){
  const int row  = blockIdx.x*4 + (threadIdx.x >> 6);
  const int lane = threadIdx.x & 63;
  const float4* q4p = (const float4*)(Qf + (size_t)row*F);
  float4 v0 = q4p[lane];
  float4 v1 = q4p[lane + 64];
  float s = v0.x*v0.x + v0.y*v0.y + v0.z*v0.z + v0.w*v0.w
          + v1.x*v1.x + v1.y*v1.y + v1.z*v1.z + v1.w*v1.w;
  for (int off = 32; off; off >>= 1) s += __shfl_down(s, off, 64);
  if (lane == 0) ws[OFF_QN + row] = s;
}

// ---------------- build M; blocked Cholesky (wave-shuffle diag); full blocked
//                  triangular inversion (rowS LDS, all-b128); store in rowT layout ----------------
__global__ __launch_bounds__(NTF) void k_factor(float* ws){
  __shared__ float Lp[PACKA];           // 117120 B, rowS-packed lower triangle
  __shared__ float Sb[16*228];          // 14592 B inversion stage buffer
  __shared__ float Dv[NB][NB+1];        // 1088 B Dinv of current diag block
  const int blk = blockIdx.x, p = blk / C, c = blk % C;
  const int tid = threadIdx.x;
  const int* wsI = (const int*)(ws + OFF_INT);
  const int n = wsI[c];
  const int m = T + n;
  const int* idxc = wsI + C + c*MAXN;
  const float* cf = ws + OFF_CLSF + c*8;
  const float sv = cf[3], av = cf[4], sqsa = cf[5]*cf[6];
  const float* Gp  = ws + OFF_G  + (size_t)p*T*T;
  const float* g1p = ws + OFF_G1 + p*T;
  const float  ggv = ws[OFF_GG + p];
  const float* Gmp = ws + OFF_GM + (size_t)p*T*C;
  const float gmcv = ws[OFF_GMC + p*C + c];
  const float mmv  = ws[OFF_MM  + p*C + c];

  // ---- build M in rowS layout; pads and rows >= m zeroed ----
  for (int e = tid; e < PACKA; e += NTF){
    int i = row_ofS(e);
    int j = e - rowS(i);
    float v = 0.f;
    if (i < m && j <= i){
      if (i < T){
        v = sv*(Gp[i*T + j] - g1p[i] - g1p[j] + ggv);
        if (j == i) v += 1.0f;
      } else {
        int ua = idxc[i - T];
        if (j < T){
          v = sqsa*(Gp[ua*T + j] - Gmp[j*C + c] - g1p[ua] + gmcv);
        } else {
          int ub = idxc[j - T];
          v = av*(Gp[ua*T + ub] - Gmp[ua*C + c] - Gmp[ub*C + c] + mmv);
          if (j == i) v += 1.0f;
        }
      }
    }
    Lp[e] = v;
  }
  __syncthreads();

  // ---- blocked right-looking Cholesky ----
  for (int k0 = 0; k0 < m; k0 += NB){
    // (a) diag 16x16 Cholesky + inverse inside wave 0 (no barriers)
    if (tid < 64){
      const int lane = tid;
      float a[NB];
      #pragma unroll
      for (int j = 0; j < NB; ++j){
        a[j] = 0.f;
        if (lane < NB && j <= lane) a[j] = Lp[rowS(k0+lane) + k0 + j];
      }
      #pragma unroll
      for (int k = 0; k < NB; ++k){
        float akk = __shfl(a[k], k, 64);
        float inv = rsqrtf(akk);
        a[k] *= inv;
        #pragma unroll
        for (int j = k+1; j < NB; ++j){
          float ljk = __shfl(a[k], j, 64);
          a[j] -= a[k] * ljk;
        }
      }
      float x[NB];
      #pragma unroll
      for (int i = 0; i < NB; ++i){
        float Lii = __shfl(a[i], i, 64);
        float sxx = 0.f;
        #pragma unroll
        for (int k2 = 0; k2 < i; ++k2){
          float Lik = __shfl(a[k2], i, 64);
          sxx += Lik * x[k2];
        }
        float tt = ((i == lane) ? 1.f : 0.f) - sxx;
        x[i] = tt / Lii;
      }
      if (lane < NB){
        #pragma unroll
        for (int i = 0; i < NB; ++i){
          Dv[i][lane] = (i >= lane) ? x[i] : 0.f;
          if (i >= lane) Lp[rowS(k0+i) + k0 + lane] = x[i];
        }
      }
    }
    __syncthreads();

    // (b) panel update: L[r][k0+j] = sum_{kk<=j} A[r][k0+kk] * Dinv[j][kk]
    for (int r = k0 + NB + tid; r < m; r += NTF){
      const int o = rowS(r) + k0;
      float4 A0 = *(const float4*)&Lp[o];
      float4 A1 = *(const float4*)&Lp[o+4];
      float4 A2 = *(const float4*)&Lp[o+8];
      float4 A3 = *(const float4*)&Lp[o+12];
      float ar[NB] = {A0.x,A0.y,A0.z,A0.w, A1.x,A1.y,A1.z,A1.w,
                      A2.x,A2.y,A2.z,A2.w, A3.x,A3.y,A3.z,A3.w};
      float sr[NB];
      #pragma unroll
      for (int j = 0; j < NB; ++j){
        float s = 0.f;
        #pragma unroll
        for (int kk = 0; kk <= j; ++kk) s += ar[kk] * Dv[j][kk];
        sr[j] = s;
      }
      *(float4*)&Lp[o]    = make_float4(sr[0], sr[1], sr[2], sr[3]);
      *(float4*)&Lp[o+4]  = make_float4(sr[4], sr[5], sr[6], sr[7]);
      *(float4*)&Lp[o+8]  = make_float4(sr[8], sr[9], sr[10], sr[11]);
      *(float4*)&Lp[o+12] = make_float4(sr[12], sr[13], sr[14], sr[15]);
    }
    __syncthreads();

    // (c) trailing SYRK directly from Lp (b128 reads; rows >= m are zero)
    const int rs = m - k0 - NB;
    if (rs > 0){
      const int base = k0 + NB;
      const int nt4 = (rs + 3) >> 2;
      const int ntile = (nt4*(nt4+1)) >> 1;
      for (int e2 = tid; e2 < ntile; e2 += NTF){
        const int ti = row_of(e2);
        const int tj = e2 - offr(ti);
        const int gi0 = base + 4*ti, gj0 = base + 4*tj;
        const float* pa0 = &Lp[rowS(gi0)   + k0];
        const float* pa1 = &Lp[rowS(gi0+1) + k0];
        const float* pa2 = &Lp[rowS(gi0+2) + k0];
        const float* pa3 = &Lp[rowS(gi0+3) + k0];
        const float* pb0 = &Lp[rowS(gj0)   + k0];
        const float* pb1 = &Lp[rowS(gj0+1) + k0];
        const float* pb2 = &Lp[rowS(gj0+2) + k0];
        const float* pb3 = &Lp[rowS(gj0+3) + k0];
        float acc[4][4] = {};
        #pragma unroll
        for (int kk = 0; kk < NB; kk += 4){
          float4 a0 = *(const float4*)(pa0+kk);
          float4 a1 = *(const float4*)(pa1+kk);
          float4 a2 = *(const float4*)(pa2+kk);
          float4 a3 = *(const float4*)(pa3+kk);
          float4 b0 = *(const float4*)(pb0+kk);
          float4 b1 = *(const float4*)(pb1+kk);
          float4 b2 = *(const float4*)(pb2+kk);
          float4 b3 = *(const float4*)(pb3+kk);
          acc[0][0] += a0.x*b0.x + a0.y*b0.y + a0.z*b0.z + a0.w*b0.w;
          acc[0][1] += a0.x*b1.x + a0.y*b1.y + a0.z*b1.z + a0.w*b1.w;
          acc[0][2] += a0.x*b2.x + a0.y*b2.y + a0.z*b2.z + a0.w*b2.w;
          acc[0][3] += a0.x*b3.x + a0.y*b3.y + a0.z*b3.z + a0.w*b3.w;
          acc[1][0] += a1.x*b0.x + a1.y*b0.y + a1.z*b0.z + a1.w*b0.w;
          acc[1][1] += a1.x*b1.x + a1.y*b1.y + a1.z*b1.z + a1.w*b1.w;
          acc[1][2] += a1.x*b2.x + a1.y*b2.y + a1.z*b2.z + a1.w*b2.w;
          acc[1][3] += a1.x*b3.x + a1.y*b3.y + a1.z*b3.z + a1.w*b3.w;
          acc[2][0] += a2.x*b0.x + a2.y*b0.y + a2.z*b0.z + a2.w*b0.w;
          acc[2][1] += a2.x*b1.x + a2.y*b1.y + a2.z*b1.z + a2.w*b1.w;
          acc[2][2] += a2.x*b2.x + a2.y*b2.y + a2.z*b2.z + a2.w*b2.w;
          acc[2][3] += a2.x*b3.x + a2.y*b3.y + a2.z*b3.z + a2.w*b3.w;
          acc[3][0] += a3.x*b0.x + a3.y*b0.y + a3.z*b0.z + a3.w*b0.w;
          acc[3][1] += a3.x*b1.x + a3.y*b1.y + a3.z*b1.z + a3.w*b1.w;
          acc[3][2] += a3.x*b2.x + a3.y*b2.y + a3.z*b2.z + a3.w*b2.w;
          acc[3][3] += a3.x*b3.x + a3.y*b3.y + a3.z*b3.z + a3.w*b3.w;
        }
        #pragma unroll
        for (int u = 0; u < 4; ++u){
          const int gi = gi0 + u;
          if (gi < m){
            const int og = rowS(gi);
            if (gj0 + 3 <= gi){
              float4 t = *(float4*)&Lp[og + gj0];
              t.x -= acc[u][0]; t.y -= acc[u][1]; t.z -= acc[u][2]; t.w -= acc[u][3];
              *(float4*)&Lp[og + gj0] = t;
            } else {
              #pragma unroll
              for (int v = 0; v < 4; ++v){
                const int gj = gj0 + v;
                if (gj <= gi) Lp[og + gj] -= acc[u][v];
              }
            }
          }
        }
      }
    }
    __syncthreads();
  }

  // ---- full triangular inversion in place (ascending block-rows, all b128) ----
  for (int I = 1; I < MMAX/NB; ++I){
    const int i0 = I*NB;
    const int nct = i0 >> 2;
    const int rt = tid & 3, ct = tid >> 2;
    const int rt4 = rt*4;
    const int j0 = ct*4;
    int o0 = 0, o1 = 0, o2 = 0, o3 = 0;
    if (tid < 4*nct){
      const int r0 = i0 + rt4;
      o0 = rowS(r0); o1 = rowS(r0+1); o2 = rowS(r0+2); o3 = rowS(r0+3);
      float acc[4][4] = {};
      for (int k = j0; k < i0; k += 4){
        float4 l0 = *(const float4*)&Lp[o0+k];
        float4 l1 = *(const float4*)&Lp[o1+k];
        float4 l2 = *(const float4*)&Lp[o2+k];
        float4 l3 = *(const float4*)&Lp[o3+k];
        float4 x0 = *(const float4*)&Lp[rowS(k)  +j0];
        float4 x1 = *(const float4*)&Lp[rowS(k+1)+j0];
        float4 x2 = *(const float4*)&Lp[rowS(k+2)+j0];
        float4 x3 = *(const float4*)&Lp[rowS(k+3)+j0];
        acc[0][0] += l0.x*x0.x + l0.y*x1.x + l0.z*x2.x + l0.w*x3.x;
        acc[0][1] += l0.x*x0.y + l0.y*x1.y + l0.z*x2.y + l0.w*x3.y;
        acc[0][2] += l0.x*x0.z + l0.y*x1.z + l0.z*x2.z + l0.w*x3.z;
        acc[0][3] += l0.x*x0.w + l0.y*x1.w + l0.z*x2.w + l0.w*x3.w;
        acc[1][0] += l1.x*x0.x + l1.y*x1.x + l1.z*x2.x + l1.w*x3.x;
        acc[1][1] += l1.x*x0.y + l1.y*x1.y + l1.z*x2.y + l1.w*x3.y;
        acc[1][2] += l1.x*x0.z + l1.y*x1.z + l1.z*x2.z + l1.w*x3.z;
        acc[1][3] += l1.x*x0.w + l1.y*x1.w + l1.z*x2.w + l1.w*x3.w;
        acc[2][0] += l2.x*x0.x + l2.y*x1.x + l2.z*x2.x + l2.w*x3.x;
        acc[2][1] += l2.x*x0.y + l2.y*x1.y + l2.z*x2.y + l2.w*x3.y;
        acc[2][2] += l2.x*x0.z + l2.y*x1.z + l2.z*x2.z + l2.w*x3.z;
        acc[2][3] += l2.x*x0.w + l2.y*x1.w + l2.z*x2.w + l2.w*x3.w;
        acc[3][0] += l3.x*x0.x + l3.y*x1.x + l3.z*x2.x + l3.w*x3.x;
        acc[3][1] += l3.x*x0.y + l3.y*x1.y + l3.z*x2.y + l3.w*x3.y;
        acc[3][2] += l3.x*x0.z + l3.y*x1.z + l3.z*x2.z + l3.w*x3.z;
        acc[3][3] += l3.x*x0.w + l3.y*x1.w + l3.z*x2.w + l3.w*x3.w;
      }
      *(float4*)&Sb[(rt4  )*228 + j0] = make_float4(acc[0][0], acc[0][1], acc[0][2], acc[0][3]);
      *(float4*)&Sb[(rt4+1)*228 + j0] = make_float4(acc[1][0], acc[1][1], acc[1][2], acc[1][3]);
      *(float4*)&Sb[(rt4+2)*228 + j0] = make_float4(acc[2][0], acc[2][1], acc[2][2], acc[2][3]);
      *(float4*)&Sb[(rt4+3)*228 + j0] = make_float4(acc[3][0], acc[3][1], acc[3][2], acc[3][3]);
    }
    __syncthreads();
    if (tid < 4*nct){
      float acc[4][4] = {};
      for (int s = 0; s < rt4 + 4; ++s){
        const float d0 = Lp[o0 + i0 + s];   // pads beyond row give zero
        const float d1 = Lp[o1 + i0 + s];
        const float d2 = Lp[o2 + i0 + s];
        const float d3 = Lp[o3 + i0 + s];
        const float4 sv4 = *(const float4*)&Sb[s*228 + j0];
        acc[0][0] += d0*sv4.x; acc[0][1] += d0*sv4.y; acc[0][2] += d0*sv4.z; acc[0][3] += d0*sv4.w;
        acc[1][0] += d1*sv4.x; acc[1][1] += d1*sv4.y; acc[1][2] += d1*sv4.z; acc[1][3] += d1*sv4.w;
        acc[2][0] += d2*sv4.x; acc[2][1] += d2*sv4.y; acc[2][2] += d2*sv4.z; acc[2][3] += d2*sv4.w;
        acc[3][0] += d3*sv4.x; acc[3][1] += d3*sv4.y; acc[3][2] += d3*sv4.z; acc[3][3] += d3*sv4.w;
      }
      *(float4*)&Lp[o0 + j0] = make_float4(-acc[0][0], -acc[0][1], -acc[0][2], -acc[0][3]);
      *(float4*)&Lp[o1 + j0] = make_float4(-acc[1][0], -acc[1][1], -acc[1][2], -acc[1][3]);
      *(float4*)&Lp[o2 + j0] = make_float4(-acc[2][0], -acc[2][1], -acc[2][2], -acc[2][3]);
      *(float4*)&Lp[o3 + j0] = make_float4(-acc[3][0], -acc[3][1], -acc[3][2], -acc[3][3]);
    }
    __syncthreads();
  }

  // ---- store W = L^-1 into tile-padded rowT layout (coalesced, zero-filled) ----
  float* Wg = ws + OFF_W + (size_t)blk * PACKT;
  // R=0: rows 0..63, len 64
  for (int e = tid; e < 64*64; e += NTF){
    int s = e >> 6, j = e & 63, r = s;
    Wg[e] = (r < m && j <= r) ? Lp[rowS(r) + j] : 0.f;
  }
  // R=1: rows 64..127, len 128
  for (int e = tid; e < 64*128; e += NTF){
    int s = e >> 7, j = e & 127, r = 64 + s;
    Wg[4096 + e] = (r < m && j <= r) ? Lp[rowS(r) + j] : 0.f;
  }
  // R=2: rows 128..191, len 192
  for (int e = tid; e < 64*192; e += NTF){
    int x = e >> 6;
    int s = (x*171) >> 9;            // x/3 for x < 512
    int j = e - s*192, r = 128 + s;
    Wg[12288 + e] = (r < m && j <= r) ? Lp[rowS(r) + j] : 0.f;
  }
  // R=3: rows 192..255, len 256
  for (int e = tid; e < 64*256; e += NTF){
    int s = e >> 8, j = e & 255, r = 192 + s;
    Wg[24576 + e] = (r < m && j <= r) ? Lp[rowS(r) + j] : 0.f;
  }
}

// ---------------- apply: z = W*e, barrier-free k-loop. W from global (rowT,
//                  zero-padded), e from LDS. 8 rows x 4 q per thread; two
//                  128-thread halves cover row-tiles {0,2} and {1,3}. ----------------
__global__ __launch_bounds__(256) void k_apply(float* ws){
  __shared__ float E[256][64];        // e (zero-padded to 256 rows); 64 KB
  __shared__ float Rb[16][64];        // reduce buffer; 4 KB
  const int p = blockIdx.z, c = blockIdx.y, q0 = blockIdx.x*64;
  const int tid = threadIdx.x;
  const int* wsI = (const int*)(ws + OFF_INT);
  const int n = wsI[c], m = T + n;
  const int* idxc = wsI + C + c*MAXN;
  const float* cf = ws + OFF_CLSF + c*8;
  const float sqs = cf[5], sqa = cf[6];
  const float gmcv = ws[OFF_GMC + p*C + c];
  const float mmv  = ws[OFF_MM  + p*C + c];
  const float* Gmp = ws + OFF_GM + (size_t)p*T*C;
  const float* SQp = ws + OFF_SQ + (size_t)p*T*NQ;
  const float* gqp = ws + OFF_GQ + p*NQ + q0;
  const float* qnp = ws + OFF_QN + p*NQ + q0;
  const float* mqp = ws + OFF_MQ + ((size_t)(p*C + c))*NQ + q0;
  const float* Wg  = ws + OFF_W + (size_t)(p*C + c)*PACKT;

  // ---- build E rows 0..255 (zero pad >= m) ----
  for (int lin = tid; lin < 256*64; lin += 256){
    int j = lin >> 6, ql = lin & 63;
    float v = 0.f;
    if (j < T){
      v = sqs*(Gmp[j*C + c] - SQp[j*NQ + q0 + ql] - gmcv + gqp[ql]);
    } else if (j < m){
      int u = idxc[j - T];
      v = sqa*(Gmp[u*C + c] - SQp[u*NQ + q0 + ql] - mmv + mqp[ql]);
    }
    E[j][ql] = v;
  }
  __syncthreads();

  const int half = tid >> 7;          // 0: row-tiles 0,2 ; 1: row-tiles 1,3
  const int lt   = tid & 127;
  const int rg8  = (lt >> 4) * 8;     // 8 rows within the 64-row tile
  const int cg4  = (lt & 15) * 4;     // 4 query columns
  float ss0 = 0.f, ss1 = 0.f, ss2 = 0.f, ss3 = 0.f;

  #pragma unroll
  for (int pass = 0; pass < 2; ++pass){
    const int R = half + 2*pass;
    const int kext = (R + 1) << 6;
    const float* base = Wg + rowT(R*64 + rg8);     // 8 rows, stride kext
    float acc[8][4] = {};
    #pragma unroll 2
    for (int k = 0; k < kext; k += 4){
      const float4 e0 = *(const float4*)&E[k  ][cg4];
      const float4 e1 = *(const float4*)&E[k+1][cg4];
      const float4 e2 = *(const float4*)&E[k+2][cg4];
      const float4 e3 = *(const float4*)&E[k+3][cg4];
      #pragma unroll
      for (int u = 0; u < 8; ++u){
        const float4 w = *(const float4*)(base + u*kext + k);
        acc[u][0] += w.x*e0.x + w.y*e1.x + w.z*e2.x + w.w*e3.x;
        acc[u][1] += w.x*e0.y + w.y*e1.y + w.z*e2.y + w.w*e3.y;
        acc[u][2] += w.x*e0.z + w.y*e1.z + w.z*e2.z + w.w*e3.z;
        acc[u][3] += w.x*e0.w + w.y*e1.w + w.z*e2.w + w.w*e3.w;
      }
    }
    #pragma unroll
    for (int u = 0; u < 8; ++u){
      ss0 += acc[u][0]*acc[u][0];
      ss1 += acc[u][1]*acc[u][1];
      ss2 += acc[u][2]*acc[u][2];
      ss3 += acc[u][3]*acc[u][3];
    }
  }

  const int gid = tid >> 4;           // 0..15 distinct (half,rg) groups
  Rb[gid][cg4 + 0] = ss0;
  Rb[gid][cg4 + 1] = ss1;
  Rb[gid][cg4 + 2] = ss2;
  Rb[gid][cg4 + 3] = ss3;
  __syncthreads();
  if (tid < 64){
    float tt = 0.f;
    #pragma unroll
    for (int g = 0; g < 16; ++g) tt += Rb[g][tid];
    float quad = mmv - 2.f*mqp[tid] + qnp[tid] - tt;
    ws[OFF_QUAD + ((size_t)p*NQ + q0 + tid)*C + c] = quad;
  }
}

// ---------------- logits: mean over p ----------------
__global__ void k_logits(const float* ws, float* out){
  int lin = blockIdx.x*256 + threadIdx.x;
  if (lin < QL){
    float s = 0.f;
    for (int p = 0; p < P; ++p) s += ws[OFF_QUAD + (size_t)p*NQ*C + lin];
    out[lin] = -s * (1.0f/P);
  }
}

extern "C" void kernel_launch(void* const* d_in, const int* in_sizes, int n_in,
                              void* d_out, int out_size, void* d_ws, size_t ws_size,
                              hipStream_t stream){
  const float* X   = (const float*)d_in[0];
  const int*   lab = (const int*)d_in[1];
  const float* Qf  = (const float*)d_in[2];
  float* out = (float*)d_out;
  float* ws  = (float*)d_ws;

  k_setup   <<<1, 64, 0, stream>>>(lab, ws);
  k_gram    <<<dim3(7,7,P),  dim3(16,16), 0, stream>>>(X, ws);
  k_pstats_a<<<dim3(25,P), 256, 0, stream>>>(ws);
  k_pstats_b<<<P, 256, 0, stream>>>(ws);
  k_means   <<<P*C, 256, 0, stream>>>(X, ws, out);
  k_sq      <<<dim3(7,16,P), dim3(16,16), 0, stream>>>(X, Qf, ws);
  k_qstats  <<<dim3(16,P), 256, 0, stream>>>(ws);
  k_qnorm   <<<(P*NQ)/4, 256, 0, stream>>>(Qf, ws);
  k_factor  <<<P*C, NTF, 0, stream>>>(ws);
  k_apply   <<<dim3(16,C,P), 256, 0, stream>>>(ws);
  k_logits  <<<QL/256, 256, 0, stream>>>(ws, out);
}

// Round 12
// 821.591 us; speedup vs baseline: 1.2503x; 1.2503x over previous
//
#include <hip/hip_runtime.h>

// Problem constants (fixed by the reference)
#define P 8
#define T 200
#define C 20
#define F 512
#define NQ 1024
#define MAXN 40                    // max samples per class we support (true ~10±4)
#define MMAX (T + MAXN)            // 240
#define PACK ((MMAX*(MMAX+1))/2)   // 28920 packed lower-tri floats
#define PACKA 29280                // row-padded-to-4 packed layout = rowS(MMAX) (LDS layout)
#define PACKT 40960                // tile-padded layout: row r padded to ((r>>6)+1)*64 cols (global W)
#define QL (NQ*C)                  // 20480 logits
#define NB 16                      // Cholesky panel width
#define NTF 512                    // k_factor block size (8 waves; 1024 forced VGPR<=64 -> spills, R7)

// Workspace layout (float offsets)
enum : int {
  OFF_G    = 0,                       // P*T*T      = 320000
  OFF_SQ   = OFF_G   + P*T*T,         // P*T*NQ     = 1638400
  OFF_G1   = OFF_SQ  + P*T*NQ,        // P*T
  OFF_GG   = OFF_G1  + P*T,           // P
  OFF_GM   = OFF_GG  + P,             // P*T*C
  OFF_GMC  = OFF_GM  + P*T*C,         // P*C
  OFF_MM   = OFF_GMC + P*C,           // P*C
  OFF_GQ   = OFF_MM  + P*C,           // P*NQ
  OFF_QN   = OFF_GQ  + P*NQ,          // P*NQ
  OFF_MQ   = OFF_QN  + P*NQ,          // P*C*NQ
  OFF_W    = OFF_MQ  + P*C*NQ,        // P*C*PACKT : W=L^-1, tile-padded rows, zeros beyond diag & rows>=m
  OFF_QUAD = OFF_W   + P*C*PACKT,     // P*NQ*C
  OFF_CLSF = OFF_QUAD+ P*NQ*C,        // C*8 scalars
  OFF_INT  = OFF_CLSF+ C*8            // int region: counts[C], idx[C*MAXN]
};

__device__ __forceinline__ int offr(int i){ return (i*(i+1))>>1; }

// 4-aligned row-padded packed layout (LDS): row i at rowS(i).
__device__ __forceinline__ int rowS(int i){
  int a = i >> 2, r = i & 3;
  return 8*a*(a+1) + 4*r*(a+1);
}

// tile-padded layout (global W): row r at rowT(r), length ((r>>6)+1)*64.
__device__ __forceinline__ int rowT(int r){
  const int R = r >> 6, s = r & 63;
  const int base = 4096 * ((R*(R+1)) >> 1);   // 0,4096,12288,24576
  return base + s*((R+1) << 6);
}

// flat packed index e -> row i (offr layout, used for tile triangles)
__device__ __forceinline__ int row_of(int e){
  int i = (int)((sqrtf(8.f*(float)e + 1.f) - 1.f) * 0.5f);
  while (offr(i+1) <= e) ++i;
  while (offr(i) > e) --i;
  return i;
}

// flat index e -> row i in rowS layout
__device__ __forceinline__ int row_ofS(int e){
  int i = (int)sqrtf(2.f*(float)e);
  if (i > MMAX-1) i = MMAX-1;
  while (i < MMAX-1 && rowS(i+1) <= e) ++i;
  while (i > 0 && rowS(i) > e) --i;
  return i;
}

// ---------------- setup: counts, per-class index lists, scalars ----------------
__global__ void k_setup(const int* lab, float* ws){
  int c = threadIdx.x;
  if (c >= C) return;
  int* wsI = (int*)(ws + OFF_INT);
  int n = 0;
  for (int t = 0; t < T; ++t){
    if (lab[t] == c){ if (n < MAXN) wsI[C + c*MAXN + n] = t; ++n; }
  }
  if (n > MAXN) n = MAXN;
  wsI[c] = n;
  float nf    = (float)n;
  float nsafe = fmaxf(nf, 1.0f);
  float dn    = fmaxf(nf - 1.0f, 1.0f);
  float lam   = nsafe / (nsafe + 1.0f);
  float sv    = (1.0f - lam) / (float)(T - 1);
  float av    = lam / dn;
  float* cf = ws + OFF_CLSF + c*8;
  cf[0] = nsafe; cf[1] = dn; cf[2] = lam; cf[3] = sv; cf[4] = av;
  cf[5] = sqrtf(sv); cf[6] = sqrtf(av); cf[7] = 0.0f;
}

// ---------------- G = X X^T per p (200x200) ----------------
__global__ __launch_bounds__(256) void k_gram(const float* X, float* ws){
  __shared__ float Xi[32][33];
  __shared__ float Xj[32][33];
  const int p = blockIdx.z, i0 = blockIdx.y*32, j0 = blockIdx.x*32;
  const int tx = threadIdx.x, ty = threadIdx.y;
  const int tid = ty*16 + tx;
  const float* Xp = X + (size_t)p*T*F;
  float acc[2][2] = {{0.f,0.f},{0.f,0.f}};
  for (int kb = 0; kb < F; kb += 32){
    for (int e = tid; e < 32*32; e += 256){
      int r = e >> 5, kk = e & 31;
      Xi[r][kk] = (i0+r < T) ? Xp[(i0+r)*F + kb+kk] : 0.f;
      Xj[r][kk] = (j0+r < T) ? Xp[(j0+r)*F + kb+kk] : 0.f;
    }
    __syncthreads();
    for (int kk = 0; kk < 32; ++kk){
      float a0 = Xi[2*ty][kk],   a1 = Xi[2*ty+1][kk];
      float b0 = Xj[2*tx][kk],   b1 = Xj[2*tx+1][kk];
      acc[0][0] += a0*b0; acc[0][1] += a0*b1;
      acc[1][0] += a1*b0; acc[1][1] += a1*b1;
    }
    __syncthreads();
  }
  float* Gp = ws + OFF_G + (size_t)p*T*T;
  for (int a = 0; a < 2; ++a)
    for (int b = 0; b < 2; ++b){
      int i = i0 + 2*ty + a, j = j0 + 2*tx + b;
      if (i < T && j < T) Gp[i*T + j] = acc[a][b];
    }
}

// ---------------- per-p stats part A: g1 rows + Gm (coalesced, 200 blocks) ----------------
__global__ __launch_bounds__(256) void k_pstats_a(float* ws){
  const int p = blockIdx.y, bx = blockIdx.x;      // bx in [0,25)
  const int w = threadIdx.x >> 6, lane = threadIdx.x & 63;
  const int* wsI = (const int*)(ws + OFF_INT);
  const float* Gp = ws + OFF_G + (size_t)p*T*T;
  float* g1 = ws + OFF_G1 + p*T;
  float* Gm = ws + OFF_GM + (size_t)p*T*C;
  for (int rr = 0; rr < 2; ++rr){
    const int t = bx*8 + w*2 + rr;                // 25*8 = 200 rows exactly
    float s = 0.f;
    for (int u = lane; u < T; u += 64) s += Gp[t*T + u];
    for (int off = 32; off; off >>= 1) s += __shfl_down(s, off, 64);
    if (lane == 0) g1[t] = s * (1.0f/T);
    if (lane < C){
      int c = lane, nn = wsI[c];
      const int* idxc = wsI + C + c*MAXN;
      float sc = 0.f;
      for (int j = 0; j < nn; ++j) sc += Gp[t*T + idxc[j]];
      Gm[t*C + c] = sc / ws[OFF_CLSF + c*8];
    }
  }
}

// ---------------- per-p stats part B: gg, gmc, mm ----------------
__global__ __launch_bounds__(256) void k_pstats_b(float* ws){
  __shared__ float red[64];
  const int p = blockIdx.x, tid = threadIdx.x;
  const int* wsI = (const int*)(ws + OFF_INT);
  const float* g1 = ws + OFF_G1 + p*T;
  const float* Gm = ws + OFF_GM + (size_t)p*T*C;
  if (tid < 64){
    float s = 0.f;
    for (int t = tid; t < T; t += 64) s += g1[t];
    red[tid] = s;
  }
  __syncthreads();
  if (tid == 0){
    float s = 0.f;
    for (int k = 0; k < 64; ++k) s += red[k];
    ws[OFF_GG + p] = s * (1.0f/T);
  }
  if (tid < C){
    int c = tid, nn = wsI[c];
    const int* idxc = wsI + C + c*MAXN;
    float s = 0.f;
    for (int t = 0; t < T; ++t) s += Gm[t*C + c];
    ws[OFF_GMC + p*C + c] = s * (1.0f/T);
    float s2 = 0.f;
    for (int j = 0; j < nn; ++j) s2 += Gm[idxc[j]*C + c];
    ws[OFF_MM + p*C + c] = s2 / ws[OFF_CLSF + c*8];
  }
}

// ---------------- class means -> output part 2 ----------------
__global__ __launch_bounds__(256) void k_means(const float* X, const float* ws, float* out){
  const int blk = blockIdx.x, p = blk / C, c = blk % C;
  const int* wsI = (const int*)(ws + OFF_INT);
  const int n = wsI[c];
  const int* idxc = wsI + C + c*MAXN;
  const float nf = ws[OFF_CLSF + c*8];
  const float* Xp = X + (size_t)p*T*F;
  float* o = out + QL + (size_t)(p*C + c)*F;
  for (int f = threadIdx.x; f < F; f += 256){
    float s = 0.f;
    for (int j = 0; j < n; ++j) s += Xp[idxc[j]*F + f];
    o[f] = s / nf;
  }
}

// ---------------- SQ = X Q^T per p (200x1024) ----------------
__global__ __launch_bounds__(256) void k_sq(const float* X, const float* Qf, float* ws){
  __shared__ float Xt[32][33];
  __shared__ float Qt[64][33];
  const int p = blockIdx.z, t0 = blockIdx.x*32, q0 = blockIdx.y*64;
  const int tx = threadIdx.x, ty = threadIdx.y;
  const int tid = ty*16 + tx;
  const float* Xp = X  + (size_t)p*T*F;
  const float* Qp = Qf + (size_t)p*NQ*F;
  float acc[2][4] = {};
  for (int kb = 0; kb < F; kb += 32){
    for (int e = tid; e < 32*32; e += 256){
      int r = e >> 5, kk = e & 31;
      Xt[r][kk] = (t0+r < T) ? Xp[(t0+r)*F + kb+kk] : 0.f;
    }
    for (int e = tid; e < 64*32; e += 256){
      int r = e >> 5, kk = e & 31;
      Qt[r][kk] = Qp[(q0+r)*F + kb+kk];
    }
    __syncthreads();
    for (int kk = 0; kk < 32; ++kk){
      float a0 = Xt[2*ty][kk], a1 = Xt[2*ty+1][kk];
      float b0 = Qt[4*tx][kk], b1 = Qt[4*tx+1][kk], b2 = Qt[4*tx+2][kk], b3 = Qt[4*tx+3][kk];
      acc[0][0] += a0*b0; acc[0][1] += a0*b1; acc[0][2] += a0*b2; acc[0][3] += a0*b3;
      acc[1][0] += a1*b0; acc[1][1] += a1*b1; acc[1][2] += a1*b2; acc[1][3] += a1*b3;
    }
    __syncthreads();
  }
  float* SQp = ws + OFF_SQ + (size_t)p*T*NQ;
  for (int a = 0; a < 2; ++a){
    int t = t0 + 2*ty + a;
    if (t < T)
      for (int b = 0; b < 4; ++b)
        SQp[t*NQ + q0 + 4*tx + b] = acc[a][b];
  }
}

// ---------------- per-q stats: gq, mq (chunked, 128 blocks) ----------------
__global__ __launch_bounds__(256) void k_qstats(float* ws){
  __shared__ float red[4][64];
  const int p = blockIdx.y;
  const int qb = blockIdx.x*64;                   // gridDim.x = 16
  const int chunk = threadIdx.x >> 6, lane = threadIdx.x & 63;
  const int q = qb + lane;
  const int* wsI = (const int*)(ws + OFF_INT);
  const float* SQp = ws + OFF_SQ + (size_t)p*T*NQ;
  float s = 0.f;
  for (int t = chunk*50; t < chunk*50 + 50; ++t) s += SQp[t*NQ + q];
  red[chunk][lane] = s;
  __syncthreads();
  if (chunk == 0){
    float tot = red[0][lane] + red[1][lane] + red[2][lane] + red[3][lane];
    ws[OFF_GQ + p*NQ + q] = tot * (1.0f/T);
  }
  for (int c = chunk; c < C; c += 4){
    int nn = wsI[c];
    const int* idxc = wsI + C + c*MAXN;
    float sc = 0.f;
    for (int j = 0; j < nn; ++j) sc += SQp[idxc[j]*NQ + q];
    ws[OFF_MQ + ((size_t)(p*C + c))*NQ + q] = sc / ws[OFF_CLSF + c*8];
  }
}

// ---------------- qn = ||q||^2, one wave per row ----------------
__global__ __launch_bounds__(256) void k_qnorm(const float* Qf, float* ws){
  const int row  = blockIdx.x*4 + (threadIdx.x >> 6);
  const int lane = threadIdx.x & 63;
  const float4* q4p = (const float4*)(Qf + (size_t)row*F);
  float4 v0 = q4p[lane];
  float4 v1 = q4p[lane + 64];
  float s = v0.x*v0.x + v0.y*v0.y + v0.z*v0.z + v0.w*v0.w
          + v1.x*v1.x + v1.y*v1.y + v1.z*v1.z + v1.w*v1.w;
  for (int off = 32; off; off >>= 1) s += __shfl_down(s, off, 64);
  if (lane == 0) ws[OFF_QN + row] = s;
}

// ---------------- build M; blocked Cholesky (wave-shuffle diag); full blocked
//                  triangular inversion (rowS LDS, all-b128); store in rowT layout ----------------
__global__ __launch_bounds__(NTF) void k_factor(float* ws){
  __shared__ float Lp[PACKA];           // 117120 B, rowS-packed lower triangle
  __shared__ float Sb[16*228];          // 14592 B inversion stage buffer
  __shared__ float Dv[NB][NB+1];        // 1088 B Dinv of current diag block
  const int blk = blockIdx.x, p = blk / C, c = blk % C;
  const int tid = threadIdx.x;
  const int* wsI = (const int*)(ws + OFF_INT);
  const int n = wsI[c];
  const int m = T + n;
  const int* idxc = wsI + C + c*MAXN;
  const float* cf = ws + OFF_CLSF + c*8;
  const float sv = cf[3], av = cf[4], sqsa = cf[5]*cf[6];
  const float* Gp  = ws + OFF_G  + (size_t)p*T*T;
  const float* g1p = ws + OFF_G1 + p*T;
  const float  ggv = ws[OFF_GG + p];
  const float* Gmp = ws + OFF_GM + (size_t)p*T*C;
  const float gmcv = ws[OFF_GMC + p*C + c];
  const float mmv  = ws[OFF_MM  + p*C + c];

  // ---- build M in rowS layout; pads and rows >= m zeroed ----
  for (int e = tid; e < PACKA; e += NTF){
    int i = row_ofS(e);
    int j = e - rowS(i);
    float v = 0.f;
    if (i < m && j <= i){
      if (i < T){
        v = sv*(Gp[i*T + j] - g1p[i] - g1p[j] + ggv);
        if (j == i) v += 1.0f;
      } else {
        int ua = idxc[i - T];
        if (j < T){
          v = sqsa*(Gp[ua*T + j] - Gmp[j*C + c] - g1p[ua] + gmcv);
        } else {
          int ub = idxc[j - T];
          v = av*(Gp[ua*T + ub] - Gmp[ua*C + c] - Gmp[ub*C + c] + mmv);
          if (j == i) v += 1.0f;
        }
      }
    }
    Lp[e] = v;
  }
  __syncthreads();

  // ---- blocked right-looking Cholesky ----
  for (int k0 = 0; k0 < m; k0 += NB){
    // (a) diag 16x16 Cholesky + inverse inside wave 0 (no barriers)
    if (tid < 64){
      const int lane = tid;
      float a[NB];
      #pragma unroll
      for (int j = 0; j < NB; ++j){
        a[j] = 0.f;
        if (lane < NB && j <= lane) a[j] = Lp[rowS(k0+lane) + k0 + j];
      }
      #pragma unroll
      for (int k = 0; k < NB; ++k){
        float akk = __shfl(a[k], k, 64);
        float inv = rsqrtf(akk);
        a[k] *= inv;
        #pragma unroll
        for (int j = k+1; j < NB; ++j){
          float ljk = __shfl(a[k], j, 64);
          a[j] -= a[k] * ljk;
        }
      }
      float x[NB];
      #pragma unroll
      for (int i = 0; i < NB; ++i){
        float Lii = __shfl(a[i], i, 64);
        float sxx = 0.f;
        #pragma unroll
        for (int k2 = 0; k2 < i; ++k2){
          float Lik = __shfl(a[k2], i, 64);
          sxx += Lik * x[k2];
        }
        float tt = ((i == lane) ? 1.f : 0.f) - sxx;
        x[i] = tt / Lii;
      }
      if (lane < NB){
        #pragma unroll
        for (int i = 0; i < NB; ++i){
          Dv[i][lane] = (i >= lane) ? x[i] : 0.f;
          if (i >= lane) Lp[rowS(k0+i) + k0 + lane] = x[i];
        }
      }
    }
    __syncthreads();

    // (b) panel update: L[r][k0+j] = sum_{kk<=j} A[r][k0+kk] * Dinv[j][kk]
    for (int r = k0 + NB + tid; r < m; r += NTF){
      const int o = rowS(r) + k0;
      float4 A0 = *(const float4*)&Lp[o];
      float4 A1 = *(const float4*)&Lp[o+4];
      float4 A2 = *(const float4*)&Lp[o+8];
      float4 A3 = *(const float4*)&Lp[o+12];
      float ar[NB] = {A0.x,A0.y,A0.z,A0.w, A1.x,A1.y,A1.z,A1.w,
                      A2.x,A2.y,A2.z,A2.w, A3.x,A3.y,A3.z,A3.w};
      float sr[NB];
      #pragma unroll
      for (int j = 0; j < NB; ++j){
        float s = 0.f;
        #pragma unroll
        for (int kk = 0; kk <= j; ++kk) s += ar[kk] * Dv[j][kk];
        sr[j] = s;
      }
      *(float4*)&Lp[o]    = make_float4(sr[0], sr[1], sr[2], sr[3]);
      *(float4*)&Lp[o+4]  = make_float4(sr[4], sr[5], sr[6], sr[7]);
      *(float4*)&Lp[o+8]  = make_float4(sr[8], sr[9], sr[10], sr[11]);
      *(float4*)&Lp[o+12] = make_float4(sr[12], sr[13], sr[14], sr[15]);
    }
    __syncthreads();

    // (c) trailing SYRK directly from Lp (b128 reads; rows >= m are zero)
    const int rs = m - k0 - NB;
    if (rs > 0){
      const int base = k0 + NB;
      const int nt4 = (rs + 3) >> 2;
      const int ntile = (nt4*(nt4+1)) >> 1;
      for (int e2 = tid; e2 < ntile; e2 += NTF){
        const int ti = row_of(e2);
        const int tj = e2 - offr(ti);
        const int gi0 = base + 4*ti, gj0 = base + 4*tj;
        const float* pa0 = &Lp[rowS(gi0)   + k0];
        const float* pa1 = &Lp[rowS(gi0+1) + k0];
        const float* pa2 = &Lp[rowS(gi0+2) + k0];
        const float* pa3 = &Lp[rowS(gi0+3) + k0];
        const float* pb0 = &Lp[rowS(gj0)   + k0];
        const float* pb1 = &Lp[rowS(gj0+1) + k0];
        const float* pb2 = &Lp[rowS(gj0+2) + k0];
        const float* pb3 = &Lp[rowS(gj0+3) + k0];
        float acc[4][4] = {};
        #pragma unroll
        for (int kk = 0; kk < NB; kk += 4){
          float4 a0 = *(const float4*)(pa0+kk);
          float4 a1 = *(const float4*)(pa1+kk);
          float4 a2 = *(const float4*)(pa2+kk);
          float4 a3 = *(const float4*)(pa3+kk);
          float4 b0 = *(const float4*)(pb0+kk);
          float4 b1 = *(const float4*)(pb1+kk);
          float4 b2 = *(const float4*)(pb2+kk);
          float4 b3 = *(const float4*)(pb3+kk);
          acc[0][0] += a0.x*b0.x + a0.y*b0.y + a0.z*b0.z + a0.w*b0.w;
          acc[0][1] += a0.x*b1.x + a0.y*b1.y + a0.z*b1.z + a0.w*b1.w;
          acc[0][2] += a0.x*b2.x + a0.y*b2.y + a0.z*b2.z + a0.w*b2.w;
          acc[0][3] += a0.x*b3.x + a0.y*b3.y + a0.z*b3.z + a0.w*b3.w;
          acc[1][0] += a1.x*b0.x + a1.y*b0.y + a1.z*b0.z + a1.w*b0.w;
          acc[1][1] += a1.x*b1.x + a1.y*b1.y + a1.z*b1.z + a1.w*b1.w;
          acc[1][2] += a1.x*b2.x + a1.y*b2.y + a1.z*b2.z + a1.w*b2.w;
          acc[1][3] += a1.x*b3.x + a1.y*b3.y + a1.z*b3.z + a1.w*b3.w;
          acc[2][0] += a2.x*b0.x + a2.y*b0.y + a2.z*b0.z + a2.w*b0.w;
          acc[2][1] += a2.x*b1.x + a2.y*b1.y + a2.z*b1.z + a2.w*b1.w;
          acc[2][2] += a2.x*b2.x + a2.y*b2.y + a2.z*b2.z + a2.w*b2.w;
          acc[2][3] += a2.x*b3.x + a2.y*b3.y + a2.z*b3.z + a2.w*b3.w;
          acc[3][0] += a3.x*b0.x + a3.y*b0.y + a3.z*b0.z + a3.w*b0.w;
          acc[3][1] += a3.x*b1.x + a3.y*b1.y + a3.z*b1.z + a3.w*b1.w;
          acc[3][2] += a3.x*b2.x + a3.y*b2.y + a3.z*b2.z + a3.w*b2.w;
          acc[3][3] += a3.x*b3.x + a3.y*b3.y + a3.z*b3.z + a3.w*b3.w;
        }
        #pragma unroll
        for (int u = 0; u < 4; ++u){
          const int gi = gi0 + u;
          if (gi < m){
            const int og = rowS(gi);
            if (gj0 + 3 <= gi){
              float4 t = *(float4*)&Lp[og + gj0];
              t.x -= acc[u][0]; t.y -= acc[u][1]; t.z -= acc[u][2]; t.w -= acc[u][3];
              *(float4*)&Lp[og + gj0] = t;
            } else {
              #pragma unroll
              for (int v = 0; v < 4; ++v){
                const int gj = gj0 + v;
                if (gj <= gi) Lp[og + gj] -= acc[u][v];
              }
            }
          }
        }
      }
    }
    __syncthreads();
  }

  // ---- full triangular inversion in place (ascending block-rows, all b128) ----
  for (int I = 1; I < MMAX/NB; ++I){
    const int i0 = I*NB;
    const int nct = i0 >> 2;
    const int rt = tid & 3, ct = tid >> 2;
    const int rt4 = rt*4;
    const int j0 = ct*4;
    int o0 = 0, o1 = 0, o2 = 0, o3 = 0;
    if (tid < 4*nct){
      const int r0 = i0 + rt4;
      o0 = rowS(r0); o1 = rowS(r0+1); o2 = rowS(r0+2); o3 = rowS(r0+3);
      float acc[4][4] = {};
      for (int k = j0; k < i0; k += 4){
        float4 l0 = *(const float4*)&Lp[o0+k];
        float4 l1 = *(const float4*)&Lp[o1+k];
        float4 l2 = *(const float4*)&Lp[o2+k];
        float4 l3 = *(const float4*)&Lp[o3+k];
        float4 x0 = *(const float4*)&Lp[rowS(k)  +j0];
        float4 x1 = *(const float4*)&Lp[rowS(k+1)+j0];
        float4 x2 = *(const float4*)&Lp[rowS(k+2)+j0];
        float4 x3 = *(const float4*)&Lp[rowS(k+3)+j0];
        acc[0][0] += l0.x*x0.x + l0.y*x1.x + l0.z*x2.x + l0.w*x3.x;
        acc[0][1] += l0.x*x0.y + l0.y*x1.y + l0.z*x2.y + l0.w*x3.y;
        acc[0][2] += l0.x*x0.z + l0.y*x1.z + l0.z*x2.z + l0.w*x3.z;
        acc[0][3] += l0.x*x0.w + l0.y*x1.w + l0.z*x2.w + l0.w*x3.w;
        acc[1][0] += l1.x*x0.x + l1.y*x1.x + l1.z*x2.x + l1.w*x3.x;
        acc[1][1] += l1.x*x0.y + l1.y*x1.y + l1.z*x2.y + l1.w*x3.y;
        acc[1][2] += l1.x*x0.z + l1.y*x1.z + l1.z*x2.z + l1.w*x3.z;
        acc[1][3] += l1.x*x0.w + l1.y*x1.w + l1.z*x2.w + l1.w*x3.w;
        acc[2][0] += l2.x*x0.x + l2.y*x1.x + l2.z*x2.x + l2.w*x3.x;
        acc[2][1] += l2.x*x0.y + l2.y*x1.y + l2.z*x2.y + l2.w*x3.y;
        acc[2][2] += l2.x*x0.z + l2.y*x1.z + l2.z*x2.z + l2.w*x3.z;
        acc[2][3] += l2.x*x0.w + l2.y*x1.w + l2.z*x2.w + l2.w*x3.w;
        acc[3][0] += l3.x*x0.x + l3.y*x1.x + l3.z*x2.x + l3.w*x3.x;
        acc[3][1] += l3.x*x0.y + l3.y*x1.y + l3.z*x2.y + l3.w*x3.y;
        acc[3][2] += l3.x*x0.z + l3.y*x1.z + l3.z*x2.z + l3.w*x3.z;
        acc[3][3] += l3.x*x0.w + l3.y*x1.w + l3.z*x2.w + l3.w*x3.w;
      }
      *(float4*)&Sb[(rt4  )*228 + j0] = make_float4(acc[0][0], acc[0][1], acc[0][2], acc[0][3]);
      *(float4*)&Sb[(rt4+1)*228 + j0] = make_float4(acc[1][0], acc[1][1], acc[1][2], acc[1][3]);
      *(float4*)&Sb[(rt4+2)*228 + j0] = make_float4(acc[2][0], acc[2][1], acc[2][2], acc[2][3]);
      *(float4*)&Sb[(rt4+3)*228 + j0] = make_float4(acc[3][0], acc[3][1], acc[3][2], acc[3][3]);
    }
    __syncthreads();
    if (tid < 4*nct){
      float acc[4][4] = {};
      for (int s = 0; s < rt4 + 4; ++s){
        const float d0 = Lp[o0 + i0 + s];   // pads beyond row give zero
        const float d1 = Lp[o1 + i0 + s];
        const float d2 = Lp[o2 + i0 + s];
        const float d3 = Lp[o3 + i0 + s];
        const float4 sv4 = *(const float4*)&Sb[s*228 + j0];
        acc[0][0] += d0*sv4.x; acc[0][1] += d0*sv4.y; acc[0][2] += d0*sv4.z; acc[0][3] += d0*sv4.w;
        acc[1][0] += d1*sv4.x; acc[1][1] += d1*sv4.y; acc[1][2] += d1*sv4.z; acc[1][3] += d1*sv4.w;
        acc[2][0] += d2*sv4.x; acc[2][1] += d2*sv4.y; acc[2][2] += d2*sv4.z; acc[2][3] += d2*sv4.w;
        acc[3][0] += d3*sv4.x; acc[3][1] += d3*sv4.y; acc[3][2] += d3*sv4.z; acc[3][3] += d3*sv4.w;
      }
      *(float4*)&Lp[o0 + j0] = make_float4(-acc[0][0], -acc[0][1], -acc[0][2], -acc[0][3]);
      *(float4*)&Lp[o1 + j0] = make_float4(-acc[1][0], -acc[1][1], -acc[1][2], -acc[1][3]);
      *(float4*)&Lp[o2 + j0] = make_float4(-acc[2][0], -acc[2][1], -acc[2][2], -acc[2][3]);
      *(float4*)&Lp[o3 + j0] = make_float4(-acc[3][0], -acc[3][1], -acc[3][2], -acc[3][3]);
    }
    __syncthreads();
  }

  // ---- store W = L^-1 into tile-padded rowT layout (coalesced, zero-filled) ----
  float* Wg = ws + OFF_W + (size_t)blk * PACKT;
  // R=0: rows 0..63, len 64
  for (int e = tid; e < 64*64; e += NTF){
    int s = e >> 6, j = e & 63, r = s;
    Wg[e] = (r < m && j <= r) ? Lp[rowS(r) + j] : 0.f;
  }
  // R=1: rows 64..127, len 128
  for (int e = tid; e < 64*128; e += NTF){
    int s = e >> 7, j = e & 127, r = 64 + s;
    Wg[4096 + e] = (r < m && j <= r) ? Lp[rowS(r) + j] : 0.f;
  }
  // R=2: rows 128..191, len 192
  for (int e = tid; e < 64*192; e += NTF){
    int x = e >> 6;
    int s = (x*171) >> 9;            // x/3 for x < 512
    int j = e - s*192, r = 128 + s;
    Wg[12288 + e] = (r < m && j <= r) ? Lp[rowS(r) + j] : 0.f;
  }
  // R=3: rows 192..255, len 256
  for (int e = tid; e < 64*256; e += NTF){
    int s = e >> 8, j = e & 255, r = 192 + s;
    Wg[24576 + e] = (r < m && j <= r) ? Lp[rowS(r) + j] : 0.f;
  }
}

// ---------------- apply: z = W*e. WAVE-PER-TILE: wave w owns row-tile w
//                  (rows 64w..64w+63, kext=64(w+1)); stages its own W chunks
//                  (16 k x 64 r, transposed) into a private LDS slice with
//                  explicit s_waitcnt lgkmcnt(0) HW fences. 8r x 8q register
//                  tiles -> 1 b128 per 16 FMA.
//                  R11 BUGFIX: final reduce read g=0..31 flat but partials
//                  were published per-slice (wv*1024 + g*64) — waves 2,3 were
//                  dropped and stale staging data summed instead. Publish is
//                  now DENSE (g = wv*8 + rgroup -> flat g*64) with a
//                  __syncthreads() before it (dense region aliases other
//                  waves' staging slices; they may still be in their k-loop). ----------------
__global__ __launch_bounds__(256) void k_apply(float* ws){
  __shared__ float E[256][64];        // e (zero-padded to 256 rows); 64 KB
  __shared__ float Wt[4][16][64];     // per-wave staging slice; 16 KB (reused as reduce buf)
  const int p = blockIdx.z, c = blockIdx.y, q0 = blockIdx.x*64;
  const int tid = threadIdx.x;
  const int* wsI = (const int*)(ws + OFF_INT);
  const int n = wsI[c], m = T + n;
  const int* idxc = wsI + C + c*MAXN;
  const float* cf = ws + OFF_CLSF + c*8;
  const float sqs = cf[5], sqa = cf[6];
  const float gmcv = ws[OFF_GMC + p*C + c];
  const float mmv  = ws[OFF_MM  + p*C + c];
  const float* Gmp = ws + OFF_GM + (size_t)p*T*C;
  const float* SQp = ws + OFF_SQ + (size_t)p*T*NQ;
  const float* gqp = ws + OFF_GQ + p*NQ + q0;
  const float* qnp = ws + OFF_QN + p*NQ + q0;
  const float* mqp = ws + OFF_MQ + ((size_t)(p*C + c))*NQ + q0;
  const float* Wg  = ws + OFF_W + (size_t)(p*C + c)*PACKT;

  // ---- build E rows 0..255 (zero pad >= m) ----
  for (int lin = tid; lin < 256*64; lin += 256){
    int j = lin >> 6, ql = lin & 63;
    float v = 0.f;
    if (j < T){
      v = sqs*(Gmp[j*C + c] - SQp[j*NQ + q0 + ql] - gmcv + gqp[ql]);
    } else if (j < m){
      int u = idxc[j - T];
      v = sqa*(Gmp[u*C + c] - SQp[u*NQ + q0 + ql] - mmv + mqp[ql]);
    }
    E[j][ql] = v;
  }
  __syncthreads();

  const int wv = tid >> 6;            // wave id = row-tile id
  const int ln = tid & 63;
  const int rg = (ln >> 3) * 8;       // 8 rows within tile
  const int cg = (ln & 7) * 8;        // 8 query columns
  const int kext = (wv + 1) << 6;
  const float* wrow = Wg + rowT(wv*64 + ln);   // lane's staging row (zeros for rows >= m)
  float* wbuf = &Wt[wv][0][0];

  float acc[8][8] = {};

  for (int kc = 0; kc < kext; kc += 16){
    // ---- stage 16-k chunk, transposed [k][r]; lane ln loads its row ----
    float4 va = *(const float4*)(wrow + kc);
    float4 vb = *(const float4*)(wrow + kc + 4);
    float4 vc = *(const float4*)(wrow + kc + 8);
    float4 vd = *(const float4*)(wrow + kc + 12);
    float v[16] = {va.x,va.y,va.z,va.w, vb.x,vb.y,vb.z,vb.w,
                   vc.x,vc.y,vc.z,vc.w, vd.x,vd.y,vd.z,vd.w};
    #pragma unroll
    for (int i = 0; i < 16; ++i) wbuf[i*64 + ln] = v[i];   // 2-way bank alias = free
    // HW fence: drain DS writes before any lane reads them (wave-level)
    asm volatile("s_waitcnt lgkmcnt(0)" ::: "memory");

    #pragma unroll 4
    for (int kl = 0; kl < 16; ++kl){
      const float4 w0 = *(const float4*)&wbuf[kl*64 + rg];
      const float4 w1 = *(const float4*)&wbuf[kl*64 + rg + 4];
      const float4 e0 = *(const float4*)&E[kc+kl][cg];
      const float4 e1 = *(const float4*)&E[kc+kl][cg+4];
      #define FMA_ROW(u, wl) \
        acc[u][0] += (wl)*e0.x; acc[u][1] += (wl)*e0.y; acc[u][2] += (wl)*e0.z; acc[u][3] += (wl)*e0.w; \
        acc[u][4] += (wl)*e1.x; acc[u][5] += (wl)*e1.y; acc[u][6] += (wl)*e1.z; acc[u][7] += (wl)*e1.w;
      FMA_ROW(0, w0.x) FMA_ROW(1, w0.y) FMA_ROW(2, w0.z) FMA_ROW(3, w0.w)
      FMA_ROW(4, w1.x) FMA_ROW(5, w1.y) FMA_ROW(6, w1.z) FMA_ROW(7, w1.w)
      #undef FMA_ROW
    }
    // HW fence: drain DS reads before next chunk's writes overwrite the slice
    asm volatile("s_waitcnt lgkmcnt(0)" ::: "memory");
  }

  // ---- per-thread ||z||^2 partials: 8 q values ----
  float ss[8];
  #pragma unroll
  for (int vq = 0; vq < 8; ++vq){
    float s = 0.f;
    #pragma unroll
    for (int u = 0; u < 8; ++u) s += acc[u][vq]*acc[u][vq];
    ss[vq] = s;
  }
  // all waves done with their staging slices before dense publish (aliasing!)
  __syncthreads();
  {
    float* Wtf = &Wt[0][0][0];
    const int g = (wv << 3) | (ln >> 3);   // dense group 0..31
    *(float4*)&Wtf[g*64 + cg]     = make_float4(ss[0], ss[1], ss[2], ss[3]);
    *(float4*)&Wtf[g*64 + cg + 4] = make_float4(ss[4], ss[5], ss[6], ss[7]);
  }
  __syncthreads();
  if (tid < 64){
    const float* Wf = &Wt[0][0][0];
    float tt = 0.f;
    #pragma unroll
    for (int g = 0; g < 32; ++g) tt += Wf[g*64 + tid];   // 4 waves x 8 rgroups, dense
    float quad = mmv - 2.f*mqp[tid] + qnp[tid] - tt;
    ws[OFF_QUAD + ((size_t)p*NQ + q0 + tid)*C + c] = quad;
  }
}

// ---------------- logits: mean over p ----------------
__global__ void k_logits(const float* ws, float* out){
  int lin = blockIdx.x*256 + threadIdx.x;
  if (lin < QL){
    float s = 0.f;
    for (int p = 0; p < P; ++p) s += ws[OFF_QUAD + (size_t)p*NQ*C + lin];
    out[lin] = -s * (1.0f/P);
  }
}

extern "C" void kernel_launch(void* const* d_in, const int* in_sizes, int n_in,
                              void* d_out, int out_size, void* d_ws, size_t ws_size,
                              hipStream_t stream){
  const float* X   = (const float*)d_in[0];
  const int*   lab = (const int*)d_in[1];
  const float* Qf  = (const float*)d_in[2];
  float* out = (float*)d_out;
  float* ws  = (float*)d_ws;

  k_setup   <<<1, 64, 0, stream>>>(lab, ws);
  k_gram    <<<dim3(7,7,P),  dim3(16,16), 0, stream>>>(X, ws);
  k_pstats_a<<<dim3(25,P), 256, 0, stream>>>(ws);
  k_pstats_b<<<P, 256, 0, stream>>>(ws);
  k_means   <<<P*C, 256, 0, stream>>>(X, ws, out);
  k_sq      <<<dim3(7,16,P), dim3(16,16), 0, stream>>>(X, Qf, ws);
  k_qstats  <<<dim3(16,P), 256, 0, stream>>>(ws);
  k_qnorm   <<<(P*NQ)/4, 256, 0, stream>>>(Qf, ws);
  k_factor  <<<P*C, NTF, 0, stream>>>(ws);
  k_apply   <<<dim3(16,C,P), 256, 0, stream>>>(ws);
  k_logits  <<<QL/256, 256, 0, stream>>>(ws, out);
}